// Round 1
// baseline (195.406 us; speedup 1.0000x reference)
//
#include <hip/hip_runtime.h>

#define NCH   64
#define KS    7
#define PADW  3
#define H     256
#define W     256
#define TILE  64
#define HALO  (TILE + KS - 1)   // 70
#define PITCH 72                // halo row pitch in floats, 16B-aligned

// Build effective 7x7 kernel: w_eff = mk + noise*(noise_eps - mean(noise_eps))
__global__ void GaussianConvBlur_wprep(const float* __restrict__ weight,
                                       const float* __restrict__ noise,
                                       const float* __restrict__ noise_eps,
                                       float* __restrict__ wf) {
    int tid = threadIdx.x;
    if (tid < KS * KS) {
        float m = 0.f;
        #pragma unroll
        for (int i = 0; i < KS * KS; ++i) m += noise_eps[i];
        m *= (1.0f / (KS * KS));
        // weight[0,0,ky,kx] is the shared diagonal Gaussian block
        wf[tid] = weight[tid] + noise[0] * (noise_eps[tid] - m);
    }
}

__global__ __launch_bounds__(256) void GaussianConvBlur_conv(
        const float* __restrict__ in,
        const float* __restrict__ wfg,
        float* __restrict__ out) {
    __shared__ float tile[HALO * PITCH];

    const int tpp   = (H / TILE) * (W / TILE);           // tiles per plane = 16
    const int b     = blockIdx.x;
    const int plane = b / tpp;
    const int t     = b % tpp;
    const int ty0   = (t / (W / TILE)) * TILE;
    const int tx0   = (t % (W / TILE)) * TILE;

    const float* __restrict__ src = in + (size_t)plane * (H * W);

    // Hoist the 49 uniform weights into registers (uniform addr -> s_load)
    float wf[KS * KS];
    #pragma unroll
    for (int i = 0; i < KS * KS; ++i) wf[i] = wfg[i];

    // Stage 70x70 halo region into LDS (zero-padded at image edges)
    for (int i = threadIdx.x; i < HALO * HALO; i += 256) {
        int ly = i / HALO;
        int lx = i - ly * HALO;
        int gy = ty0 + ly - PADW;
        int gx = tx0 + lx - PADW;
        float v = 0.f;
        if (gy >= 0 && gy < H && gx >= 0 && gx < W) v = src[gy * W + gx];
        tile[ly * PITCH + lx] = v;
    }
    __syncthreads();

    // 16x16 thread grid, each thread computes a 4x4 output block
    const int ttx = threadIdx.x & 15;
    const int tty = threadIdx.x >> 4;
    const float* base = &tile[(tty * 4) * PITCH + ttx * 4];

    float acc[4][4] = {};

    #pragma unroll
    for (int iy = 0; iy < 10; ++iy) {
        // load 10 needed floats (r[0..9]); r[10..11] are pad garbage, unused
        float r[12];
        const float* row = base + iy * PITCH;
        *(float4*)&r[0] = *(const float4*)&row[0];
        *(float4*)&r[4] = *(const float4*)&row[4];
        *(float4*)&r[8] = *(const float4*)&row[8];

        #pragma unroll
        for (int oy = 0; oy < 4; ++oy) {
            const int ky = iy - oy;
            if (ky >= 0 && ky < KS) {
                #pragma unroll
                for (int kx = 0; kx < KS; ++kx) {
                    const float wv = wf[ky * KS + kx];
                    #pragma unroll
                    for (int ox = 0; ox < 4; ++ox)
                        acc[oy][ox] = fmaf(wv, r[ox + kx], acc[oy][ox]);
                }
            }
        }
    }

    float* dst = out + (size_t)plane * (H * W) + (ty0 + tty * 4) * W + (tx0 + ttx * 4);
    #pragma unroll
    for (int oy = 0; oy < 4; ++oy) {
        float4 v = make_float4(acc[oy][0], acc[oy][1], acc[oy][2], acc[oy][3]);
        *(float4*)(dst + (size_t)oy * W) = v;
    }
}

extern "C" void kernel_launch(void* const* d_in, const int* in_sizes, int n_in,
                              void* d_out, int out_size, void* d_ws, size_t ws_size,
                              hipStream_t stream) {
    const float* x         = (const float*)d_in[0];  // (16,64,256,256)
    const float* weight    = (const float*)d_in[1];  // (64,64,7,7)
    const float* noise     = (const float*)d_in[2];  // scalar
    const float* noise_eps = (const float*)d_in[3];  // (7,7)
    float*       out       = (float*)d_out;
    float*       wf        = (float*)d_ws;           // 49 floats scratch

    GaussianConvBlur_wprep<<<1, 64, 0, stream>>>(weight, noise, noise_eps, wf);

    const int planes = 16 * NCH;                       // 1024
    const int tpp    = (H / TILE) * (W / TILE);        // 16
    GaussianConvBlur_conv<<<planes * tpp, 256, 0, stream>>>(x, wf, out);
}

// Round 2
// 151.085 us; speedup vs baseline: 1.2934x; 1.2934x over previous
//
#include <hip/hip_runtime.h>

#define KS    7
#define H     256
#define W     256
#define STRIP 32   // output rows per wave
#define WPB   4    // waves per block (block covers 128 rows)

// Build effective 7x7 kernel: w_eff = mk + noise*(noise_eps - mean(noise_eps))
__global__ void GaussianConvBlur_wprep(const float* __restrict__ weight,
                                       const float* __restrict__ noise,
                                       const float* __restrict__ noise_eps,
                                       float* __restrict__ wf) {
    int tid = threadIdx.x;
    if (tid < KS * KS) {
        float m = 0.f;
        #pragma unroll
        for (int i = 0; i < KS * KS; ++i) m += noise_eps[i];
        m *= (1.0f / (KS * KS));
        wf[tid] = weight[tid] + noise[0] * (noise_eps[tid] - m);
    }
}

// LDS-free depthwise 7x7: each wave spans the full 256-wide row (64 lanes x
// float4); 7-deep ring of float4 accumulators slides down a 32-row strip.
__global__ __launch_bounds__(256) void GaussianConvBlur_conv(
        const float* __restrict__ in,
        const float* __restrict__ wfg,
        float* __restrict__ out) {
    const int lane = threadIdx.x & 63;
    const int wid  = threadIdx.x >> 6;

    const int plane = blockIdx.x >> 1;          // 2 blocks per plane
    const int sblk  = blockIdx.x & 1;
    const int s0    = (sblk * WPB + wid) * STRIP;

    const float* __restrict__ src = in  + (size_t)plane * (H * W);
    float*       __restrict__ dst = out + (size_t)plane * (H * W);

    // Pin the 49 uniform weights to SGPRs (one SGPR operand per FMA is free)
    float wf[KS * KS];
    #pragma unroll
    for (int i = 0; i < KS * KS; ++i)
        wf[i] = __int_as_float(__builtin_amdgcn_readfirstlane(__float_as_int(wfg[i])));

    const int x4 = lane << 2;

    float4 acc[7];
    #pragma unroll
    for (int i = 0; i < 7; ++i) acc[i] = make_float4(0.f, 0.f, 0.f, 0.f);

    const int NSTEP = STRIP + KS - 1;           // 38 input rows per strip

    for (int g = 0; g < (NSTEP + 6) / 7; ++g) { // 6 groups, 7-step unroll keeps
        #pragma unroll                          // ring indices compile-time
        for (int u = 0; u < 7; ++u) {
            const int rel = g * 7 + u;
            if (rel < NSTEP) {
                const int ri = s0 - 3 + rel;    // input row (uniform per wave)
                const bool rv = (ri >= 0) && (ri < H);
                if (rv) {
                    const float* rowp = src + ri * W + x4;
                    float4 r1 = *(const float4*)rowp;
                    float4 r0 = make_float4(0.f, 0.f, 0.f, 0.f);
                    float4 r2 = make_float4(0.f, 0.f, 0.f, 0.f);
                    if (lane > 0)  r0 = *(const float4*)(rowp - 4); // x halo
                    if (lane < 63) r2 = *(const float4*)(rowp + 4); // x halo
                    float s[10];
                    s[0] = r0.y; s[1] = r0.z; s[2] = r0.w;
                    s[3] = r1.x; s[4] = r1.y; s[5] = r1.z; s[6] = r1.w;
                    s[7] = r2.x; s[8] = r2.y; s[9] = r2.z;
                    #pragma unroll
                    for (int j = 0; j < 7; ++j) {
                        const int slot = (u + j + 4) % 7;   // static index
                        const int ky   = 6 - j;             // w row for o=ri-3+j
                        #pragma unroll
                        for (int kx = 0; kx < 7; ++kx) {
                            const float wv = wf[ky * 7 + kx];
                            acc[slot].x = fmaf(wv, s[kx],     acc[slot].x);
                            acc[slot].y = fmaf(wv, s[kx + 1], acc[slot].y);
                            acc[slot].z = fmaf(wv, s[kx + 2], acc[slot].z);
                            acc[slot].w = fmaf(wv, s[kx + 3], acc[slot].w);
                        }
                    }
                }
                // output row o = ri-3 completes this step
                const int o     = ri - 3;
                const int oslot = (u + 4) % 7;              // static index
                if (o >= s0) {                              // o < s0+STRIP holds
                    *(float4*)(dst + o * W + x4) = acc[oslot];
                }
                acc[oslot] = make_float4(0.f, 0.f, 0.f, 0.f); // recycle slot
            }
        }
    }
}

extern "C" void kernel_launch(void* const* d_in, const int* in_sizes, int n_in,
                              void* d_out, int out_size, void* d_ws, size_t ws_size,
                              hipStream_t stream) {
    const float* x         = (const float*)d_in[0];  // (16,64,256,256)
    const float* weight    = (const float*)d_in[1];  // (64,64,7,7)
    const float* noise     = (const float*)d_in[2];  // scalar
    const float* noise_eps = (const float*)d_in[3];  // (7,7)
    float*       out       = (float*)d_out;
    float*       wf        = (float*)d_ws;           // 49 floats scratch

    GaussianConvBlur_wprep<<<1, 64, 0, stream>>>(weight, noise, noise_eps, wf);

    const int planes = 16 * 64;                       // 1024 planes
    GaussianConvBlur_conv<<<planes * 2, 256, 0, stream>>>(x, wf, out);
}